// Round 6
// baseline (99.359 us; speedup 1.0000x reference)
//
#include <hip/hip_runtime.h>

// MedianBlur 3x3, zero padding, fp32, (16,3,512,512).
// R6: decouple R4's confound — RPT back to 8 (doubles occupancy to
// 6 waves/SIMD, finer load/compute/store phases, better HBM read/write
// interleave) while KEEPING the XCD swizzle (halo re-reads stay L2-local;
// 1.25x over-fetch is absorbed by L2). Stores back to nontemporal (R5 A/B
// showed cached was marginally worse).
//   - 10 dwordx4 row loads per thread, hoisted for MLP
//   - horizontal halos via __shfl_up/__shfl_down; lanes 0/63 fix-up loads
//   - median-of-9 via column-sort identity (v_min3/v_med3/v_max3)

#define MB_W 512
#define MB_H 512
#define MB_R 8   // output rows per thread

typedef float vf4 __attribute__((ext_vector_type(4)));

__device__ __forceinline__ float min3f(float a, float b, float c) {
    return fminf(fminf(a, b), c);
}
__device__ __forceinline__ float max3f(float a, float b, float c) {
    return fmaxf(fmaxf(a, b), c);
}
__device__ __forceinline__ float med3f(float a, float b, float c) {
    return __builtin_amdgcn_fmed3f(a, b, c);
}

__global__ __launch_bounds__(256) void median3x3_kernel(
    const float* __restrict__ in, float* __restrict__ out) {
    const int W = MB_W, H = MB_H;
    const int lane = threadIdx.x & 63;

    // XCD swizzle: 1536 blocks, HW XCD = blockIdx % 8.
    // logical = (blockIdx%8)*192 + blockIdx/8 -> XCD k owns 1.5 consecutive
    // planes (1.5 MB < 4 MB L2) -> vertical-halo re-reads are L2-local.
    const int nb      = gridDim.x;             // 1536
    const int chunk   = nb >> 3;               // 192
    const int logical = (blockIdx.x & 7) * chunk + (blockIdx.x >> 3);
    const int tid = logical * blockDim.x + threadIdx.x;

    // 128 col-groups (4 cols), 64 row-groups (8 rows), 48 planes.
    const int xg    = tid & 127;
    const int yg    = (tid >> 7) & 63;
    const int plane = tid >> 13;

    const int x0 = xg << 2;
    const int y0 = yg << 3;

    const float* __restrict__ p = in  + (size_t)plane * (H * W);
    float*       __restrict__ q = out + (size_t)plane * (H * W);

    // ---- Load 10 rows (y0-1 .. y0+8) as dwordx4; boundary rows zero ----
    vf4 v[MB_R + 2];
    #pragma unroll
    for (int r = 0; r < MB_R + 2; ++r) {
        const int y = y0 - 1 + r;
        if (y >= 0 && y < H) {                 // wave-uniform branch
            v[r] = *(const vf4*)(p + y * W + x0);
        } else {
            v[r] = (vf4){0.f, 0.f, 0.f, 0.f};
        }
    }

    // ---- Edge-lane fix-up loads (issued early, independent of shuffles) ----
    float lfix[MB_R + 2], rfix[MB_R + 2];
    if (lane == 0) {
        #pragma unroll
        for (int r = 0; r < MB_R + 2; ++r) {
            const int y = y0 - 1 + r;
            lfix[r] = (x0 > 0 && y >= 0 && y < H) ? p[y * W + x0 - 1] : 0.f;
        }
    }
    if (lane == 63) {
        #pragma unroll
        for (int r = 0; r < MB_R + 2; ++r) {
            const int y = y0 - 1 + r;
            rfix[r] = (x0 + 4 < W && y >= 0 && y < H) ? p[y * W + x0 + 4] : 0.f;
        }
    }

    // ---- Horizontal halos via cross-lane shuffle ----
    float lft[MB_R + 2], rgt[MB_R + 2];
    #pragma unroll
    for (int r = 0; r < MB_R + 2; ++r) {
        lft[r] = __shfl_up(v[r].w, 1);         // lane i-1's col x0-1
        rgt[r] = __shfl_down(v[r].x, 1);       // lane i+1's col x0+4
        if (lane == 0)  lft[r] = lfix[r];
        if (lane == 63) rgt[r] = rfix[r];
    }

    // ---- Median-of-9 per output row ----
    #pragma unroll
    for (int k = 0; k < MB_R; ++k) {
        const float a0[6] = {lft[k],     v[k].x,     v[k].y,     v[k].z,     v[k].w,     rgt[k]};
        const float a1[6] = {lft[k + 1], v[k + 1].x, v[k + 1].y, v[k + 1].z, v[k + 1].w, rgt[k + 1]};
        const float a2[6] = {lft[k + 2], v[k + 2].x, v[k + 2].y, v[k + 2].z, v[k + 2].w, rgt[k + 2]};

        float lo[6], md[6], hi[6];
        #pragma unroll
        for (int j = 0; j < 6; ++j) {
            lo[j] = min3f(a0[j], a1[j], a2[j]);
            md[j] = med3f(a0[j], a1[j], a2[j]);
            hi[j] = max3f(a0[j], a1[j], a2[j]);
        }

        vf4 o;
        #pragma unroll
        for (int i = 0; i < 4; ++i) {
            const float mx = max3f(lo[i], lo[i + 1], lo[i + 2]);
            const float mm = med3f(md[i], md[i + 1], md[i + 2]);
            const float mn = min3f(hi[i], hi[i + 1], hi[i + 2]);
            o[i] = med3f(mx, mm, mn);
        }
        __builtin_nontemporal_store(o, (vf4*)(q + (y0 + k) * W + x0));
    }
}

extern "C" void kernel_launch(void* const* d_in, const int* in_sizes, int n_in,
                              void* d_out, int out_size, void* d_ws, size_t ws_size,
                              hipStream_t stream) {
    const float* in = (const float*)d_in[0];
    float* out = (float*)d_out;
    // 48 planes * 64 row-groups * 128 col-groups = 393216 threads
    const int total_threads = 48 * 64 * 128;
    const int block = 256;
    const int grid = total_threads / block;    // 1536 blocks
    median3x3_kernel<<<grid, block, 0, stream>>>(in, out);
}

// Round 7
// 97.607 us; speedup vs baseline: 1.0179x; 1.0179x over previous
//
#include <hip/hip_runtime.h>

// MedianBlur 3x3, zero padding, fp32, (16,3,512,512).
// R7: R4 (best: RPT=16, XCD swizzle, nt stores) + per-k incremental halo
// production: lft/rgt for row k+2 computed just before median k, so median
// compute of row k only depends on rows <= k+2 and overlaps the in-flight
// loads of rows k+3..17 within the wave (R4 produced all 18 halos in one
// phase, serializing the full load drain before any median).
//   - 18 dwordx4 row loads hoisted in one burst (MLP)
//   - horizontal halos via __shfl_up/__shfl_down; lanes 0/63 fix-up
//   - median-of-9 via column-sort identity (v_min3/v_med3/v_max3)

#define MB_W 512
#define MB_H 512
#define MB_R 16   // output rows per thread

typedef float vf4 __attribute__((ext_vector_type(4)));

__device__ __forceinline__ float min3f(float a, float b, float c) {
    return fminf(fminf(a, b), c);
}
__device__ __forceinline__ float max3f(float a, float b, float c) {
    return fmaxf(fmaxf(a, b), c);
}
__device__ __forceinline__ float med3f(float a, float b, float c) {
    return __builtin_amdgcn_fmed3f(a, b, c);
}

__global__ __launch_bounds__(256) void median3x3_kernel(
    const float* __restrict__ in, float* __restrict__ out) {
    const int W = MB_W, H = MB_H;
    const int lane = threadIdx.x & 63;

    // XCD swizzle: 768 blocks, HW XCD = blockIdx % 8.
    const int nb      = gridDim.x;             // 768
    const int chunk   = nb >> 3;               // 96
    const int logical = (blockIdx.x & 7) * chunk + (blockIdx.x >> 3);
    const int tid = logical * blockDim.x + threadIdx.x;

    // 128 col-groups (4 cols), 32 row-groups (16 rows), 48 planes.
    const int xg    = tid & 127;
    const int yg    = (tid >> 7) & 31;
    const int plane = tid >> 12;

    const int x0 = xg << 2;
    const int y0 = yg << 4;

    const float* __restrict__ p = in  + (size_t)plane * (H * W);
    float*       __restrict__ q = out + (size_t)plane * (H * W);

    // ---- Load 18 rows (y0-1 .. y0+16) as dwordx4; boundary rows zero ----
    vf4 v[MB_R + 2];
    #pragma unroll
    for (int r = 0; r < MB_R + 2; ++r) {
        const int y = y0 - 1 + r;
        if (y >= 0 && y < H) {                 // wave-uniform branch
            v[r] = *(const vf4*)(p + y * W + x0);
        } else {
            v[r] = (vf4){0.f, 0.f, 0.f, 0.f};
        }
    }

    // Per-row halo production (shuffle + edge-lane fix-up), called lazily.
    float lft[MB_R + 2], rgt[MB_R + 2];
    auto make_halo = [&](int r) {
        lft[r] = __shfl_up(v[r].w, 1);         // lane i-1's col x0-1
        rgt[r] = __shfl_down(v[r].x, 1);       // lane i+1's col x0+4
        const int y = y0 - 1 + r;
        if (lane == 0)
            lft[r] = (x0 > 0 && y >= 0 && y < H) ? p[y * W + x0 - 1] : 0.f;
        if (lane == 63)
            rgt[r] = (x0 + 4 < W && y >= 0 && y < H) ? p[y * W + x0 + 4] : 0.f;
    };

    make_halo(0);
    make_halo(1);

    // ---- Median-of-9 per output row; halo for row k+2 made just-in-time ----
    #pragma unroll
    for (int k = 0; k < MB_R; ++k) {
        make_halo(k + 2);                      // only dep on v[k+2] beyond row k+1

        const float a0[6] = {lft[k],     v[k].x,     v[k].y,     v[k].z,     v[k].w,     rgt[k]};
        const float a1[6] = {lft[k + 1], v[k + 1].x, v[k + 1].y, v[k + 1].z, v[k + 1].w, rgt[k + 1]};
        const float a2[6] = {lft[k + 2], v[k + 2].x, v[k + 2].y, v[k + 2].z, v[k + 2].w, rgt[k + 2]};

        float lo[6], md[6], hi[6];
        #pragma unroll
        for (int j = 0; j < 6; ++j) {
            lo[j] = min3f(a0[j], a1[j], a2[j]);
            md[j] = med3f(a0[j], a1[j], a2[j]);
            hi[j] = max3f(a0[j], a1[j], a2[j]);
        }

        vf4 o;
        #pragma unroll
        for (int i = 0; i < 4; ++i) {
            const float mx = max3f(lo[i], lo[i + 1], lo[i + 2]);
            const float mm = med3f(md[i], md[i + 1], md[i + 2]);
            const float mn = min3f(hi[i], hi[i + 1], hi[i + 2]);
            o[i] = med3f(mx, mm, mn);
        }
        __builtin_nontemporal_store(o, (vf4*)(q + (y0 + k) * W + x0));
    }
}

extern "C" void kernel_launch(void* const* d_in, const int* in_sizes, int n_in,
                              void* d_out, int out_size, void* d_ws, size_t ws_size,
                              hipStream_t stream) {
    const float* in = (const float*)d_in[0];
    float* out = (float*)d_out;
    // 48 planes * 32 row-groups * 128 col-groups = 196608 threads
    const int total_threads = 48 * 32 * 128;
    const int block = 256;
    const int grid = total_threads / block;    // 768 blocks
    median3x3_kernel<<<grid, block, 0, stream>>>(in, out);
}

// Round 8
// 95.039 us; speedup vs baseline: 1.0455x; 1.0270x over previous
//
#include <hip/hip_runtime.h>

// MedianBlur 3x3, zero padding, fp32, (16,3,512,512).
// R8 = exact revert to R4, the measured best (95.7 us).
// Experiment matrix (kernel-attributable deltas):
//   RPT 8->16          : -3.5 us  (over-fetch 1.25x->1.125x, fewer per-row ovh)
//   XCD swizzle        : neutral  (working set is L3-resident anyway)
//   nt vs cached store : neutral  (nt marginally better, kept)
//   2x occupancy (R6)  : +3.7 us  (worse)
//   JIT halo sched (R7): +1.9 us  (worse - compiler already pipelines via vmcnt)
// Decomposition: kernel ~22 us vs 16.0 us compulsory-traffic floor
// (100.7 MB @ 6.29 TB/s); dur_us remainder ~74 us is fixed harness reset
// traffic (d_ws/d_out poison + d_in restore), not addressable from the kernel.
//   - 18 dwordx4 row loads per thread, hoisted in one burst (MLP)
//   - horizontal halos via __shfl_up/__shfl_down; lanes 0/63 fix-up loads
//   - median-of-9 via column-sort identity (v_min3/v_med3/v_max3)
//   - nontemporal dwordx4 stores

#define MB_W 512
#define MB_H 512
#define MB_R 16   // output rows per thread

typedef float vf4 __attribute__((ext_vector_type(4)));

__device__ __forceinline__ float min3f(float a, float b, float c) {
    return fminf(fminf(a, b), c);
}
__device__ __forceinline__ float max3f(float a, float b, float c) {
    return fmaxf(fmaxf(a, b), c);
}
__device__ __forceinline__ float med3f(float a, float b, float c) {
    return __builtin_amdgcn_fmed3f(a, b, c);
}

__global__ __launch_bounds__(256) void median3x3_kernel(
    const float* __restrict__ in, float* __restrict__ out) {
    const int W = MB_W, H = MB_H;
    const int lane = threadIdx.x & 63;

    // XCD swizzle: 768 blocks, HW XCD = blockIdx % 8.
    // logical = (blockIdx%8)*96 + blockIdx/8 -> XCD k owns 3 consecutive planes.
    const int nb      = gridDim.x;             // 768
    const int chunk   = nb >> 3;               // 96
    const int logical = (blockIdx.x & 7) * chunk + (blockIdx.x >> 3);
    const int tid = logical * blockDim.x + threadIdx.x;

    // 128 col-groups (4 cols), 32 row-groups (16 rows), 48 planes.
    const int xg    = tid & 127;
    const int yg    = (tid >> 7) & 31;
    const int plane = tid >> 12;

    const int x0 = xg << 2;
    const int y0 = yg << 4;

    const float* __restrict__ p = in  + (size_t)plane * (H * W);
    float*       __restrict__ q = out + (size_t)plane * (H * W);

    // ---- Load 18 rows (y0-1 .. y0+16) as dwordx4; boundary rows zero ----
    vf4 v[MB_R + 2];
    #pragma unroll
    for (int r = 0; r < MB_R + 2; ++r) {
        const int y = y0 - 1 + r;
        if (y >= 0 && y < H) {                 // wave-uniform branch
            v[r] = *(const vf4*)(p + y * W + x0);
        } else {
            v[r] = (vf4){0.f, 0.f, 0.f, 0.f};
        }
    }

    // ---- Horizontal halos via cross-lane shuffle ----
    float lft[MB_R + 2], rgt[MB_R + 2];
    #pragma unroll
    for (int r = 0; r < MB_R + 2; ++r) {
        lft[r] = __shfl_up(v[r].w, 1);         // lane i-1's col x0-1
        rgt[r] = __shfl_down(v[r].x, 1);       // lane i+1's col x0+4
    }
    // Fix-up wave-edge lanes (1 active lane -> 1 cache line each).
    if (lane == 0) {
        #pragma unroll
        for (int r = 0; r < MB_R + 2; ++r) {
            const int y = y0 - 1 + r;
            lft[r] = (x0 > 0 && y >= 0 && y < H) ? p[y * W + x0 - 1] : 0.f;
        }
    }
    if (lane == 63) {
        #pragma unroll
        for (int r = 0; r < MB_R + 2; ++r) {
            const int y = y0 - 1 + r;
            rgt[r] = (x0 + 4 < W && y >= 0 && y < H) ? p[y * W + x0 + 4] : 0.f;
        }
    }

    // ---- Median-of-9 per output row ----
    #pragma unroll
    for (int k = 0; k < MB_R; ++k) {
        const float a0[6] = {lft[k],     v[k].x,     v[k].y,     v[k].z,     v[k].w,     rgt[k]};
        const float a1[6] = {lft[k + 1], v[k + 1].x, v[k + 1].y, v[k + 1].z, v[k + 1].w, rgt[k + 1]};
        const float a2[6] = {lft[k + 2], v[k + 2].x, v[k + 2].y, v[k + 2].z, v[k + 2].w, rgt[k + 2]};

        float lo[6], md[6], hi[6];
        #pragma unroll
        for (int j = 0; j < 6; ++j) {
            lo[j] = min3f(a0[j], a1[j], a2[j]);
            md[j] = med3f(a0[j], a1[j], a2[j]);
            hi[j] = max3f(a0[j], a1[j], a2[j]);
        }

        vf4 o;
        #pragma unroll
        for (int i = 0; i < 4; ++i) {
            const float mx = max3f(lo[i], lo[i + 1], lo[i + 2]);
            const float mm = med3f(md[i], md[i + 1], md[i + 2]);
            const float mn = min3f(hi[i], hi[i + 1], hi[i + 2]);
            o[i] = med3f(mx, mm, mn);
        }
        __builtin_nontemporal_store(o, (vf4*)(q + (y0 + k) * W + x0));
    }
}

extern "C" void kernel_launch(void* const* d_in, const int* in_sizes, int n_in,
                              void* d_out, int out_size, void* d_ws, size_t ws_size,
                              hipStream_t stream) {
    const float* in = (const float*)d_in[0];
    float* out = (float*)d_out;
    // 48 planes * 32 row-groups * 128 col-groups = 196608 threads
    const int total_threads = 48 * 32 * 128;
    const int block = 256;
    const int grid = total_threads / block;    // 768 blocks
    median3x3_kernel<<<grid, block, 0, stream>>>(in, out);
}